// Round 15
// baseline (94.548 us; speedup 1.0000x reference)
//
#include <hip/hip_runtime.h>
#include <math.h>

#define BB 256
#define VV 4096
#define DD 64
#define NCH 64        // 64 chunks x 64 rows
#define CHB 16384     // chunk bytes: 64 rows x 64 d x 4 B
#define SLICE 4096    // per-wave slice: 16 rows x 256 B
#define RING 4        // private ring buffers per wave (16 KB/wave, 128 KB total)

typedef __attribute__((ext_vector_type(8))) _Float16 f16x8;
typedef __attribute__((ext_vector_type(2))) __fp16 fp16x2;
typedef __attribute__((ext_vector_type(4))) float f32x4;
typedef __attribute__((address_space(3))) void lds_void_t;
typedef const __attribute__((address_space(1))) void gvoid_t;

// ---------------------------------------------------------------------------
// Kernel 1: one block (512 thr, 8 waves) per a.  wave = (rg, hf):
//   rg = wave>>1 in [0,4): rows rg*16..rg*16+16 of each 64-row chunk,
//   hf = wave&1: cols [128*hf, 128*hf+128).
// ZERO barriers: each wave stages ITS OWN 16 rows into a PRIVATE 4-buf LDS
// ring (depth-3, counted vmcnt(12)) and never waits on other waves.
// r11/r12/r14 post-mortems: the per-chunk cross-wave s_barrier re-phases all
// waves to the slowest condition each chunk => phases sum. Removing it lets
// DMA/ds_read/VALU/MFMA of different waves overlap freely.
// Rows are staged by BOTH col-half waves (2x DMA issue); the duplicate hits
// L1/L2 (co-resident, loosely synced) so HBM traffic stays ~1x.
// ---------------------------------------------------------------------------
__global__ __launch_bounds__(512) void topk_sim_kernel(
    const float* __restrict__ F, const float* __restrict__ lan,
    float* __restrict__ max0P, float* __restrict__ max1P)
{
  extern __shared__ __align__(16) char smem[];   // 8 waves x 16 KB private
  const int t = threadIdx.x;
  const int a = blockIdx.x;
  const int wave = t >> 6;
  const int lane = t & 63;
  const int cl = lane & 15;      // A-row / B-col / C-col within 16x16 tile
  const int o  = lane >> 4;      // k-octet group
  const int rg = wave >> 1;      // row quarter of each 64-row chunk
  const int hf = wave & 1;       // col half

  char* mybuf = smem + (size_t)wave * (RING * SLICE);
  const char* gFa = (const char*)(F + (size_t)a * VV * DD);

  // ---- B fragments: 8 col-tiles x 2 ksubs, fp16 (64 VGPR) ----
  f16x8 bf[8][2];
#pragma unroll
  for (int ct = 0; ct < 8; ++ct)
#pragma unroll
    for (int s = 0; s < 2; ++s) {
      const float* p = lan + (hf * 128 + ct * 16 + cl) * DD + s * 32 + o * 8;
      float4 u0 = *(const float4*)p, u1 = *(const float4*)(p + 4);
      union { f16x8 v; fp16x2 h[4]; } U;
      U.h[0] = __builtin_amdgcn_cvt_pkrtz(u0.x, u0.y);
      U.h[1] = __builtin_amdgcn_cvt_pkrtz(u0.z, u0.w);
      U.h[2] = __builtin_amdgcn_cvt_pkrtz(u1.x, u1.y);
      U.h[3] = __builtin_amdgcn_cvt_pkrtz(u1.z, u1.w);
      bf[ct][s] = U.v;
    }

  // pre-swizzled per-lane source offsets within a chunk (G21: linear LDS
  // dest, inverse-swizzled source, swizzled read).  DMA i covers local rows
  // 4i..4i+4 of this wave's 16-row slice; lane (o,cl) -> row 4i+o, slot cl.
  int soff[4];
#pragma unroll
  for (int i = 0; i < 4; ++i) {
    int rl = i * 4 + o;                          // local row in [0,16)
    soff[i] = (rg * 16 + rl) * 256 + (cl ^ (rl & 7)) * 16;
  }

  auto stage = [&](int ch, char* buf) {
    const char* g = gFa + (size_t)ch * CHB;
#pragma unroll
    for (int i = 0; i < 4; ++i) {
      __builtin_amdgcn_global_load_lds(
          (gvoid_t*)(g + soff[i]),
          (lds_void_t*)(buf + i * 1024), 16, 0, 0);
    }
  };

  // ---- prologue: stage chunks 0,1,2 (12 DMAs in flight) ----
  stage(0, mybuf);
  stage(1, mybuf + SLICE);
  stage(2, mybuf + 2 * SLICE);

  float m0[8], m1[8];
#pragma unroll
  for (int ct = 0; ct < 8; ++ct) { m0[ct] = -INFINITY; m1[ct] = -INFINITY; }

  auto compute = [&](const char* buf) {
    const int rx = cl & 7;
    const char* rp = buf + cl * 256;             // local row = cl
    float4 u00 = *(const float4*)(rp + ((((o * 2 + 0) ^ rx)) << 4));
    float4 u01 = *(const float4*)(rp + ((((o * 2 + 1) ^ rx)) << 4));
    float4 u10 = *(const float4*)(rp + ((8 + ((o * 2 + 0) ^ rx)) << 4));
    float4 u11 = *(const float4*)(rp + ((8 + ((o * 2 + 1) ^ rx)) << 4));
    union { f16x8 v; fp16x2 h[4]; } A0, A1;
    A0.h[0] = __builtin_amdgcn_cvt_pkrtz(u00.x, u00.y);
    A0.h[1] = __builtin_amdgcn_cvt_pkrtz(u00.z, u00.w);
    A0.h[2] = __builtin_amdgcn_cvt_pkrtz(u01.x, u01.y);
    A0.h[3] = __builtin_amdgcn_cvt_pkrtz(u01.z, u01.w);
    A1.h[0] = __builtin_amdgcn_cvt_pkrtz(u10.x, u10.y);
    A1.h[1] = __builtin_amdgcn_cvt_pkrtz(u10.z, u10.w);
    A1.h[2] = __builtin_amdgcn_cvt_pkrtz(u11.x, u11.y);
    A1.h[3] = __builtin_amdgcn_cvt_pkrtz(u11.z, u11.w);
#pragma unroll
    for (int ct = 0; ct < 8; ++ct) {
      f32x4 acc = {0.f, 0.f, 0.f, 0.f};
      acc = __builtin_amdgcn_mfma_f32_16x16x32_f16(A0.v, bf[ct][0], acc, 0, 0, 0);
      acc = __builtin_amdgcn_mfma_f32_16x16x32_f16(A1.v, bf[ct][1], acc, 0, 0, 0);
      float h1 = fmaxf(acc[0], acc[1]), q1 = fminf(acc[0], acc[1]);
      float h2 = fmaxf(acc[2], acc[3]), q2 = fminf(acc[2], acc[3]);
      float M0 = fmaxf(h1, h2);
      float M1 = fmaxf(fminf(h1, h2), fmaxf(q1, q2));
      float old0 = m0[ct];
      m0[ct] = fmaxf(old0, M0);
      m1[ct] = fmaxf(m1[ct], fmaxf(fminf(old0, M0), M1));
    }
  };

  // ---- main loop: wave-private depth-3 pipeline, NO barriers ----
#pragma unroll 1
  for (int ch = 0; ch < NCH; ++ch) {
    if (ch + 3 < NCH) {
      stage(ch + 3, mybuf + (size_t)((ch + 3) & 3) * SLICE);
      asm volatile("s_waitcnt vmcnt(12)" ::: "memory");   // my ch delivered
    } else {
      const int rem = NCH - 1 - ch;
      if (rem == 2)      asm volatile("s_waitcnt vmcnt(8)" ::: "memory");
      else if (rem == 1) asm volatile("s_waitcnt vmcnt(4)" ::: "memory");
      else               asm volatile("s_waitcnt vmcnt(0)" ::: "memory");
    }
    __builtin_amdgcn_sched_barrier(0);
    compute(mybuf + (size_t)(ch & 3) * SLICE);
  }

  // ---- merge across the 4 k-octet groups within the wave; store ----
#pragma unroll
  for (int ct = 0; ct < 8; ++ct) {
#pragma unroll
    for (int off = 16; off <= 32; off <<= 1) {
      float p0 = __shfl_xor(m0[ct], off);
      float p1 = __shfl_xor(m1[ct], off);
      float n1 = fmaxf(fminf(m0[ct], p0), fmaxf(m1[ct], p1));
      m0[ct] = fmaxf(m0[ct], p0);
      m1[ct] = n1;
    }
    if (lane < 16) {
      const int col = hf * 128 + ct * 16 + lane;
      max0P[((size_t)a * 4 + rg) * BB + col] = m0[ct];
      max1P[((size_t)a * 4 + rg) * BB + col] = m1[ct];
    }
  }
}

// ---------------------------------------------------------------------------
// Kernel 2: per row b, merge the 4 row-group partials per a, LSE over 511
// logits, loss_b = LSE - diag.
// ---------------------------------------------------------------------------
__global__ __launch_bounds__(256) void lse_kernel(
    const float* __restrict__ max0P, const float* __restrict__ max1P,
    float* __restrict__ lossb)
{
  __shared__ float red[256];
  __shared__ float diag;
  const int b = blockIdx.x;
  const int t = threadIdx.x;     // t = a
  float M0 = -INFINITY, M1 = -INFINITY;
#pragma unroll
  for (int q = 0; q < 4; ++q) {
    float p0 = max0P[((size_t)t * 4 + q) * BB + b];
    float p1 = max1P[((size_t)t * 4 + q) * BB + b];
    float n1 = fmaxf(fminf(M0, p0), fmaxf(M1, p1));
    M0 = fmaxf(M0, p0);
    M1 = n1;
  }
  float x0 = M0;
  float x1 = (t == b) ? -INFINITY : M1;
  if (t == b) diag = x0;
  red[t] = fmaxf(x0, x1);
  __syncthreads();
  for (int s = 128; s > 0; s >>= 1) {
    if (t < s) red[t] = fmaxf(red[t], red[t + s]);
    __syncthreads();
  }
  float M = red[0];
  __syncthreads();
  float e = expf(x0 - M) + ((t == b) ? 0.0f : expf(x1 - M));
  red[t] = e;
  __syncthreads();
  for (int s = 128; s > 0; s >>= 1) {
    if (t < s) red[t] = red[t] + red[t + s];
    __syncthreads();
  }
  if (t == 0) lossb[b] = logf(red[0]) + M - diag;
}

__global__ __launch_bounds__(256) void mean_kernel(
    const float* __restrict__ lossb, float* __restrict__ out)
{
  __shared__ float red[256];
  const int t = threadIdx.x;
  red[t] = lossb[t];
  __syncthreads();
  for (int s = 128; s > 0; s >>= 1) {
    if (t < s) red[t] += red[t + s];
    __syncthreads();
  }
  if (t == 0) out[0] = red[0] * (1.0f / 256.0f);
}

extern "C" void kernel_launch(void* const* d_in, const int* in_sizes, int n_in,
                              void* d_out, int out_size, void* d_ws, size_t ws_size,
                              hipStream_t stream) {
  const float* F   = (const float*)d_in[0];   // fusion_fs [256,4096,64] fp32
  const float* lan = (const float*)d_in[1];   // lan_fs    [256,1,64]   fp32
  float* ws = (float*)d_ws;
  float* max0P = ws;                // [256*4*256] = 1 MB
  float* max1P = ws + 262144;       // [256*4*256] = 1 MB
  float* lossb = ws + 524288;       // [256]

  const int shmem = 8 * RING * SLICE;   // 128 KB
  hipFuncSetAttribute((const void*)topk_sim_kernel,
                      hipFuncAttributeMaxDynamicSharedMemorySize, shmem);
  topk_sim_kernel<<<256, 512, shmem, stream>>>(F, lan, max0P, max1P);
  lse_kernel<<<256, 256, 0, stream>>>(max0P, max1P, lossb);
  mean_kernel<<<1, 256, 0, stream>>>(lossb, (float*)d_out);
}

// Round 16
// 77.151 us; speedup vs baseline: 1.2255x; 1.2255x over previous
//
#include <hip/hip_runtime.h>
#include <math.h>

#define BB 256
#define VV 4096
#define DD 64
#define NCHUNK 32
#define CHB 32768   // chunk bytes: 128 rows x 64 d x 4 B
#define NBUF 5      // 5 x 32 KB = 160 KB LDS, depth-3 pipeline

typedef __attribute__((ext_vector_type(8))) _Float16 f16x8;
typedef __attribute__((ext_vector_type(2))) __fp16 fp16x2;   // cvt_pkrtz return type
typedef __attribute__((ext_vector_type(4))) float f32x4;
typedef __attribute__((address_space(3))) void lds_void_t;
typedef const __attribute__((address_space(1))) void gvoid_t;

// ---------------------------------------------------------------------------
// Kernel 1: one block (512 thr, 8 waves) per a.  wave = rg*2+cg:
//   rg in [0,4): rows [32rg, 32rg+32) of each 128-row chunk,
//   cg in [0,2): cols [128cg, 128cg+128)  (bf[8][2] = 64 VGPR).
// r13 structure (best, 70.6us) with the wave layout flipped 2x4 -> 4x2:
// each staged row is ds_read by 2 waves instead of 4 -> LDS reads per chunk
// halve (128KB -> 64KB, ~-512 cyc of the measured serial tail), in-loop cvt
// halves too.  All else identical: 5 bufs, depth-3 counted vmcnt(12), one
// raw s_barrier per chunk.  Per-(a,rg) partials stored; lse merges 4.
// ---------------------------------------------------------------------------
__global__ __launch_bounds__(512) void topk_sim_kernel(
    const float* __restrict__ F, const float* __restrict__ lan,
    float* __restrict__ max0P, float* __restrict__ max1P)
{
  extern __shared__ __align__(16) char smem[];   // 5 x 32KB chunk buffers

  const int t = threadIdx.x;
  const int a = blockIdx.x;
  const int wave = t >> 6;
  const int lane = t & 63;
  const int cl = lane & 15;      // row (A) / col (B/C) within 16x16 tile
  const int o  = lane >> 4;      // k-octet group
  const int rg = wave >> 1;      // row quarter
  const int cg = wave & 1;       // col half

  const char* gFa = (const char*)(F + (size_t)a * VV * DD);

  // pre-swizzled per-lane global source offsets (G21: linear LDS dest,
  // inverse-swizzled source, swizzled read).  Wave stages rows [16w,16w+16).
  int soff[4];
#pragma unroll
  for (int i = 0; i < 4; ++i) {
    int row = wave * 16 + i * 4 + o;             // row in [0,128)
    soff[i] = row * 256 + (cl ^ (row & 7)) * 16;
  }

  auto stage = [&](int ch, char* buf) {
    const char* g = gFa + (size_t)ch * CHB;
    char* dst = buf + wave * 4096;               // wave-uniform base
#pragma unroll
    for (int i = 0; i < 4; ++i) {
      __builtin_amdgcn_global_load_lds(
          (gvoid_t*)(g + soff[i]),
          (lds_void_t*)(dst + i * 1024), 16, 0, 0);
    }
  };

  // ---- B fragment GLOBAL LOADS FIRST (older than all staging DMAs) ----
  float4 bu[8][2][2];
#pragma unroll
  for (int ct = 0; ct < 8; ++ct)
#pragma unroll
    for (int s = 0; s < 2; ++s) {
      const float* p = lan + (cg * 128 + ct * 16 + cl) * DD + s * 32 + o * 8;
      bu[ct][s][0] = *(const float4*)p;
      bu[ct][s][1] = *(const float4*)(p + 4);
    }

  // ---- prologue: stage chunks 0,1,2 (12 DMAs in flight) ----
  stage(0, smem);
  stage(1, smem + CHB);
  stage(2, smem + 2 * CHB);

  // ---- convert B fragments to fp16 ----
  f16x8 bf[8][2];
#pragma unroll
  for (int ct = 0; ct < 8; ++ct)
#pragma unroll
    for (int s = 0; s < 2; ++s) {
      union { f16x8 v; fp16x2 h[4]; } U;
      U.h[0] = __builtin_amdgcn_cvt_pkrtz(bu[ct][s][0].x, bu[ct][s][0].y);
      U.h[1] = __builtin_amdgcn_cvt_pkrtz(bu[ct][s][0].z, bu[ct][s][0].w);
      U.h[2] = __builtin_amdgcn_cvt_pkrtz(bu[ct][s][1].x, bu[ct][s][1].y);
      U.h[3] = __builtin_amdgcn_cvt_pkrtz(bu[ct][s][1].z, bu[ct][s][1].w);
      bf[ct][s] = U.v;
    }

  float m0[8], m1[8];
#pragma unroll
  for (int ct = 0; ct < 8; ++ct) { m0[ct] = -INFINITY; m1[ct] = -INFINITY; }

  auto compute = [&](const char* buf) {
#pragma unroll
    for (int rt = 0; rt < 2; ++rt) {
      const int row = rg * 32 + rt * 16 + cl;
      const int rx = row & 7;
      const char* rp = buf + row * 256;
      float4 u00 = *(const float4*)(rp + ((((o * 2 + 0) ^ rx)) << 4));
      float4 u01 = *(const float4*)(rp + ((((o * 2 + 1) ^ rx)) << 4));
      float4 u10 = *(const float4*)(rp + ((8 + ((o * 2 + 0) ^ rx)) << 4));
      float4 u11 = *(const float4*)(rp + ((8 + ((o * 2 + 1) ^ rx)) << 4));
      union { f16x8 v; fp16x2 h[4]; } A0, A1;
      A0.h[0] = __builtin_amdgcn_cvt_pkrtz(u00.x, u00.y);
      A0.h[1] = __builtin_amdgcn_cvt_pkrtz(u00.z, u00.w);
      A0.h[2] = __builtin_amdgcn_cvt_pkrtz(u01.x, u01.y);
      A0.h[3] = __builtin_amdgcn_cvt_pkrtz(u01.z, u01.w);
      A1.h[0] = __builtin_amdgcn_cvt_pkrtz(u10.x, u10.y);
      A1.h[1] = __builtin_amdgcn_cvt_pkrtz(u10.z, u10.w);
      A1.h[2] = __builtin_amdgcn_cvt_pkrtz(u11.x, u11.y);
      A1.h[3] = __builtin_amdgcn_cvt_pkrtz(u11.z, u11.w);
#pragma unroll
      for (int ct = 0; ct < 8; ++ct) {
        f32x4 acc = {0.f, 0.f, 0.f, 0.f};
        acc = __builtin_amdgcn_mfma_f32_16x16x32_f16(A0.v, bf[ct][0], acc, 0, 0, 0);
        acc = __builtin_amdgcn_mfma_f32_16x16x32_f16(A1.v, bf[ct][1], acc, 0, 0, 0);
        float h1 = fmaxf(acc[0], acc[1]), q1 = fminf(acc[0], acc[1]);
        float h2 = fmaxf(acc[2], acc[3]), q2 = fminf(acc[2], acc[3]);
        float M0 = fmaxf(h1, h2);
        float M1 = fmaxf(fminf(h1, h2), fmaxf(q1, q2));
        float old0 = m0[ct];
        m0[ct] = fmaxf(old0, M0);
        m1[ct] = fmaxf(m1[ct], fmaxf(fminf(old0, M0), M1));
      }
    }
  };

  // ---- main loop: depth-3 counted-vmcnt pipeline, 1 raw barrier/chunk ----
  int bcur = 0;     // buf index of chunk ch
  int bnxt = 3;     // buf index of chunk ch+3
#pragma unroll 1
  for (int ch = 0; ch < NCHUNK; ++ch) {
    if (ch + 3 < NCHUNK) {
      stage(ch + 3, smem + (size_t)bnxt * CHB);
      asm volatile("s_waitcnt vmcnt(12)" ::: "memory");   // ch delivered
    } else {
      const int rem = NCHUNK - 1 - ch;   // chunks outstanding beyond ch
      if (rem == 2)      asm volatile("s_waitcnt vmcnt(8)" ::: "memory");
      else if (rem == 1) asm volatile("s_waitcnt vmcnt(4)" ::: "memory");
      else               asm volatile("s_waitcnt vmcnt(0)" ::: "memory");
    }
    __builtin_amdgcn_s_barrier();            // everyone's ch loads done
    __builtin_amdgcn_sched_barrier(0);
    compute(smem + (size_t)bcur * CHB);
    bcur = (bcur == NBUF - 1) ? 0 : bcur + 1;
    bnxt = (bnxt == NBUF - 1) ? 0 : bnxt + 1;
  }

  // ---- merge across the 4 k-octet row-groups within the wave; store ----
#pragma unroll
  for (int ct = 0; ct < 8; ++ct) {
#pragma unroll
    for (int off = 16; off <= 32; off <<= 1) {
      float p0 = __shfl_xor(m0[ct], off);
      float p1 = __shfl_xor(m1[ct], off);
      float n1 = fmaxf(fminf(m0[ct], p0), fmaxf(m1[ct], p1));
      m0[ct] = fmaxf(m0[ct], p0);
      m1[ct] = n1;
    }
    if (lane < 16) {
      const int col = cg * 128 + ct * 16 + lane;
      max0P[((size_t)a * 4 + rg) * BB + col] = m0[ct];
      max1P[((size_t)a * 4 + rg) * BB + col] = m1[ct];
    }
  }
}

// ---------------------------------------------------------------------------
// Kernel 2: per row b, merge the 4 row-group partials per a, LSE over 511
// logits, loss_b = LSE - diag.
// ---------------------------------------------------------------------------
__global__ __launch_bounds__(256) void lse_kernel(
    const float* __restrict__ max0P, const float* __restrict__ max1P,
    float* __restrict__ lossb)
{
  __shared__ float red[256];
  __shared__ float diag;
  const int b = blockIdx.x;
  const int t = threadIdx.x;     // t = a
  float M0 = -INFINITY, M1 = -INFINITY;
#pragma unroll
  for (int q = 0; q < 4; ++q) {
    float p0 = max0P[((size_t)t * 4 + q) * BB + b];
    float p1 = max1P[((size_t)t * 4 + q) * BB + b];
    float n1 = fmaxf(fminf(M0, p0), fmaxf(M1, p1));
    M0 = fmaxf(M0, p0);
    M1 = n1;
  }
  float x0 = M0;
  float x1 = (t == b) ? -INFINITY : M1;
  if (t == b) diag = x0;
  red[t] = fmaxf(x0, x1);
  __syncthreads();
  for (int s = 128; s > 0; s >>= 1) {
    if (t < s) red[t] = fmaxf(red[t], red[t + s]);
    __syncthreads();
  }
  float M = red[0];
  __syncthreads();
  float e = expf(x0 - M) + ((t == b) ? 0.0f : expf(x1 - M));
  red[t] = e;
  __syncthreads();
  for (int s = 128; s > 0; s >>= 1) {
    if (t < s) red[t] = red[t] + red[t + s];
    __syncthreads();
  }
  if (t == 0) lossb[b] = logf(red[0]) + M - diag;
}

__global__ __launch_bounds__(256) void mean_kernel(
    const float* __restrict__ lossb, float* __restrict__ out)
{
  __shared__ float red[256];
  const int t = threadIdx.x;
  red[t] = lossb[t];
  __syncthreads();
  for (int s = 128; s > 0; s >>= 1) {
    if (t < s) red[t] += red[t + s];
    __syncthreads();
  }
  if (t == 0) out[0] = red[0] * (1.0f / 256.0f);
}

extern "C" void kernel_launch(void* const* d_in, const int* in_sizes, int n_in,
                              void* d_out, int out_size, void* d_ws, size_t ws_size,
                              hipStream_t stream) {
  const float* F   = (const float*)d_in[0];   // fusion_fs [256,4096,64] fp32
  const float* lan = (const float*)d_in[1];   // lan_fs    [256,1,64]   fp32
  float* ws = (float*)d_ws;
  float* max0P = ws;                // [256*4*256] = 1 MB
  float* max1P = ws + 262144;       // [256*4*256] = 1 MB
  float* lossb = ws + 524288;       // [256]

  const int shmem = NBUF * CHB;     // 163840 B = full 160 KB LDS
  hipFuncSetAttribute((const void*)topk_sim_kernel,
                      hipFuncAttributeMaxDynamicSharedMemorySize, shmem);
  topk_sim_kernel<<<256, 512, shmem, stream>>>(F, lan, max0P, max1P);
  lse_kernel<<<256, 256, 0, stream>>>(max0P, max1P, lossb);
  mean_kernel<<<1, 256, 0, stream>>>(lossb, (float*)d_out);
}

// Round 17
// 67.160 us; speedup vs baseline: 1.4078x; 1.1488x over previous
//
#include <hip/hip_runtime.h>
#include <math.h>

#define BB 256
#define VV 4096
#define DD 64
#define NCHUNK 32
#define CHBG 32768   // global chunk bytes: 128 rows x 64 d x 4 B (fp32)
#define CHBL 16384   // LDS chunk bytes:    128 rows x 64 d x 2 B (fp16)

typedef __attribute__((ext_vector_type(8))) _Float16 f16x8;
typedef __attribute__((ext_vector_type(2))) __fp16 fp16x2;   // cvt_pkrtz return type
typedef __attribute__((ext_vector_type(4))) float f32x4;

// ---------------------------------------------------------------------------
// Kernel 1: one block (512 thr, 8 waves) per a.  wave = rg*4+cg (r13 2x4).
// CHANGE vs r13 (best, 70.6us): F staged into LDS as FP16 via reg-staging
// (T14 issue-early/write-late), not fp32 via global_load_lds:
//   - each element cvt'd once per CU at stage time (not once per use),
//   - LDS traffic/chunk: 16KB write + 64KB read  (was 32KB DMA + 128KB read),
//   - compute phase = ds_read_b128 -> MFMA direct, no cvt.
// Schedule unchanged: depth-2 static-named reg pipeline (rule #20: E/O sets),
// counted vmcnt(4), ONE raw s_barrier per chunk, 2 LDS buffers (32 KB).
// Write swizzle: slot ^= row&7 (b64 floor); read: slot ^ (cl&7) (b128 floor).
// ---------------------------------------------------------------------------
__global__ __launch_bounds__(512) void topk_sim_kernel(
    const float* __restrict__ F, const float* __restrict__ lan,
    float* __restrict__ max0T, float* __restrict__ max1T)
{
  extern __shared__ __align__(16) char smem[];   // 2 x 16KB fp16 chunk buffers
  __shared__ float mrg[8][64][2];                // 4 KB merge buffer

  const int t = threadIdx.x;
  const int a = blockIdx.x;
  const int wave = t >> 6;
  const int lane = t & 63;
  const int cl = lane & 15;      // row (A) / col (B/C) within 16x16 tile
  const int o  = lane >> 4;      // k-octet group
  const int rg = wave >> 2;      // row half
  const int cg = wave & 3;       // col quarter

  const char* gFa = (const char*)(F + (size_t)a * VV * DD);

  // ---- B fragment loads + cvt (all vmem retired before F pipeline) ----
  float4 bu[4][2][2];
#pragma unroll
  for (int ct = 0; ct < 4; ++ct)
#pragma unroll
    for (int s = 0; s < 2; ++s) {
      const float* p = lan + (cg * 64 + ct * 16 + cl) * DD + s * 32 + o * 8;
      bu[ct][s][0] = *(const float4*)p;
      bu[ct][s][1] = *(const float4*)(p + 4);
    }
  f16x8 bf[4][2];
#pragma unroll
  for (int ct = 0; ct < 4; ++ct)
#pragma unroll
    for (int s = 0; s < 2; ++s) {
      union { f16x8 v; fp16x2 h[4]; } U;
      U.h[0] = __builtin_amdgcn_cvt_pkrtz(bu[ct][s][0].x, bu[ct][s][0].y);
      U.h[1] = __builtin_amdgcn_cvt_pkrtz(bu[ct][s][0].z, bu[ct][s][0].w);
      U.h[2] = __builtin_amdgcn_cvt_pkrtz(bu[ct][s][1].x, bu[ct][s][1].y);
      U.h[3] = __builtin_amdgcn_cvt_pkrtz(bu[ct][s][1].z, bu[ct][s][1].w);
      bf[ct][s] = U.v;
    }

  // ---- staging addressing ----
  // load: instr i covers bytes [8192*i, 8192*i+8192) of the chunk; thread t
  // takes 16B at 8192*i + 16*t  -> row_i = 32*i + (t>>4), d0 = 4*(t&15).
  // write: fp16 8B at row_i*128 + swizzled slot; slot/half constant over i.
  const int woff = ((((t & 15) >> 1) ^ ((t >> 4) & 7)) << 4) + (t & 1) * 8;
  const int wrow = (t >> 4) * 128;               // + i*4096 per instr

#define LOADG(S0, S1, S2, S3, CH) {                                   \
    const char* _g = gFa + (size_t)(CH) * CHBG + 16 * t;              \
    S0 = *(const float4*)(_g);                                        \
    S1 = *(const float4*)(_g + 8192);                                 \
    S2 = *(const float4*)(_g + 16384);                                \
    S3 = *(const float4*)(_g + 24576); }

#define CVTW(S0, S1, S2, S3, BUFP) {                                  \
    char* _b = (BUFP) + wrow + woff;                                  \
    uint2 _w;                                                         \
    union { uint2 u; fp16x2 h[2]; } _c;                               \
    _c.h[0] = __builtin_amdgcn_cvt_pkrtz(S0.x, S0.y);                 \
    _c.h[1] = __builtin_amdgcn_cvt_pkrtz(S0.z, S0.w); _w = _c.u;      \
    *(uint2*)(_b) = _w;                                               \
    _c.h[0] = __builtin_amdgcn_cvt_pkrtz(S1.x, S1.y);                 \
    _c.h[1] = __builtin_amdgcn_cvt_pkrtz(S1.z, S1.w); _w = _c.u;      \
    *(uint2*)(_b + 4096) = _w;                                        \
    _c.h[0] = __builtin_amdgcn_cvt_pkrtz(S2.x, S2.y);                 \
    _c.h[1] = __builtin_amdgcn_cvt_pkrtz(S2.z, S2.w); _w = _c.u;      \
    *(uint2*)(_b + 8192) = _w;                                        \
    _c.h[0] = __builtin_amdgcn_cvt_pkrtz(S3.x, S3.y);                 \
    _c.h[1] = __builtin_amdgcn_cvt_pkrtz(S3.z, S3.w); _w = _c.u;      \
    *(uint2*)(_b + 12288) = _w; }

  float m0[4], m1[4];
#pragma unroll
  for (int ct = 0; ct < 4; ++ct) { m0[ct] = -INFINITY; m1[ct] = -INFINITY; }

  auto compute = [&](const char* buf) {
#pragma unroll
    for (int rt = 0; rt < 4; ++rt) {
      const int row = rg * 64 + rt * 16 + cl;
      const int rx = cl & 7;                     // row&7 == cl&7
      const char* lp = buf + row * 128;
      f16x8 a0 = *(const f16x8*)(lp + ((o ^ rx) << 4));         // ksub 0
      f16x8 a1 = *(const f16x8*)(lp + (((4 + o) ^ rx) << 4));   // ksub 1
#pragma unroll
      for (int ct = 0; ct < 4; ++ct) {
        f32x4 acc = {0.f, 0.f, 0.f, 0.f};
        acc = __builtin_amdgcn_mfma_f32_16x16x32_f16(a0, bf[ct][0], acc, 0, 0, 0);
        acc = __builtin_amdgcn_mfma_f32_16x16x32_f16(a1, bf[ct][1], acc, 0, 0, 0);
        float h1 = fmaxf(acc[0], acc[1]), q1 = fminf(acc[0], acc[1]);
        float h2 = fmaxf(acc[2], acc[3]), q2 = fminf(acc[2], acc[3]);
        float M0 = fmaxf(h1, h2);
        float M1 = fmaxf(fminf(h1, h2), fmaxf(q1, q2));
        float old0 = m0[ct];
        m0[ct] = fmaxf(old0, M0);
        m1[ct] = fmaxf(m1[ct], fmaxf(fminf(old0, M0), M1));
      }
    }
  };

  char* buf0 = smem;
  char* buf1 = smem + CHBL;

  // ---- prologue: E=chunk0, O=chunk1; write chunk0 -> buf0; barrier ----
  float4 E0, E1, E2, E3, O0, O1, O2, O3;
  LOADG(E0, E1, E2, E3, 0)
  LOADG(O0, O1, O2, O3, 1)
  asm volatile("s_waitcnt vmcnt(4)" ::: "memory");   // E delivered
  CVTW(E0, E1, E2, E3, buf0)
  asm volatile("s_waitcnt lgkmcnt(0)" ::: "memory");
  __builtin_amdgcn_s_barrier();

  // ---- main loop: 15 x 2 chunks, fully regular ----
#pragma unroll 1
  for (int q = 0; q < 15; ++q) {
    const int ch = 2 * q;
    // even: consume O(ch+1)->buf1, compute buf0(ch)
    LOADG(E0, E1, E2, E3, ch + 2)
    asm volatile("s_waitcnt vmcnt(4)" ::: "memory");   // O ready
    __builtin_amdgcn_sched_barrier(0);
    CVTW(O0, O1, O2, O3, buf1)
    compute(buf0);
    asm volatile("s_waitcnt lgkmcnt(0)" ::: "memory");
    __builtin_amdgcn_s_barrier();
    // odd: consume E(ch+2)->buf0, compute buf1(ch+1)
    LOADG(O0, O1, O2, O3, ch + 3)
    asm volatile("s_waitcnt vmcnt(4)" ::: "memory");   // E ready
    __builtin_amdgcn_sched_barrier(0);
    CVTW(E0, E1, E2, E3, buf0)
    compute(buf1);
    asm volatile("s_waitcnt lgkmcnt(0)" ::: "memory");
    __builtin_amdgcn_s_barrier();
  }
  // ---- tail: chunks 30 (buf0), 31 (buf1) ----
  asm volatile("s_waitcnt vmcnt(0)" ::: "memory");     // O(31) delivered
  __builtin_amdgcn_sched_barrier(0);
  CVTW(O0, O1, O2, O3, buf1)
  compute(buf0);
  asm volatile("s_waitcnt lgkmcnt(0)" ::: "memory");
  __builtin_amdgcn_s_barrier();
  compute(buf1);
#undef LOADG
#undef CVTW

  // ---- merge across the 4 k-octet row-groups within the wave ----
#pragma unroll
  for (int ct = 0; ct < 4; ++ct) {
#pragma unroll
    for (int off = 16; off <= 32; off <<= 1) {
      float p0 = __shfl_xor(m0[ct], off);
      float p1 = __shfl_xor(m1[ct], off);
      float n1 = fmaxf(fminf(m0[ct], p0), fmaxf(m1[ct], p1));
      m0[ct] = fmaxf(m0[ct], p0);
      m1[ct] = n1;
    }
    if (lane < 16) {
      mrg[wave][ct * 16 + lane][0] = m0[ct];
      mrg[wave][ct * 16 + lane][1] = m1[ct];
    }
  }
  __syncthreads();

  // ---- merge the 2 row-half waves of each col group; store ----
  if (t < BB) {
    const int cg2 = t >> 6, lc = t & 63;   // global col == t
    float a0 = mrg[cg2][lc][0],     a1 = mrg[cg2][lc][1];
    float b0 = mrg[4 + cg2][lc][0], b1 = mrg[4 + cg2][lc][1];
    float M0 = fmaxf(a0, b0);
    float M1 = fmaxf(fminf(a0, b0), fmaxf(a1, b1));
    max0T[a * BB + t] = M0;
    max1T[a * BB + t] = M1;
  }
}

// ---------------------------------------------------------------------------
// Kernel 2: per row b, LSE over 511 logits, loss_b = LSE - diag.
// ---------------------------------------------------------------------------
__global__ __launch_bounds__(256) void lse_kernel(
    const float* __restrict__ max0T, const float* __restrict__ max1T,
    float* __restrict__ lossb)
{
  __shared__ float red[256];
  __shared__ float diag;
  const int b = blockIdx.x;
  const int t = threadIdx.x;     // t = a
  float x0 = max0T[t * BB + b];
  float x1 = (t == b) ? -INFINITY : max1T[t * BB + b];
  if (t == b) diag = x0;
  red[t] = fmaxf(x0, x1);
  __syncthreads();
  for (int s = 128; s > 0; s >>= 1) {
    if (t < s) red[t] = fmaxf(red[t], red[t + s]);
    __syncthreads();
  }
  float M = red[0];
  __syncthreads();
  float e = expf(x0 - M) + ((t == b) ? 0.0f : expf(x1 - M));
  red[t] = e;
  __syncthreads();
  for (int s = 128; s > 0; s >>= 1) {
    if (t < s) red[t] = red[t] + red[t + s];
    __syncthreads();
  }
  if (t == 0) lossb[b] = logf(red[0]) + M - diag;
}

__global__ __launch_bounds__(256) void mean_kernel(
    const float* __restrict__ lossb, float* __restrict__ out)
{
  __shared__ float red[256];
  const int t = threadIdx.x;
  red[t] = lossb[t];
  __syncthreads();
  for (int s = 128; s > 0; s >>= 1) {
    if (t < s) red[t] += red[t + s];
    __syncthreads();
  }
  if (t == 0) out[0] = red[0] * (1.0f / 256.0f);
}

extern "C" void kernel_launch(void* const* d_in, const int* in_sizes, int n_in,
                              void* d_out, int out_size, void* d_ws, size_t ws_size,
                              hipStream_t stream) {
  const float* F   = (const float*)d_in[0];   // fusion_fs [256,4096,64] fp32
  const float* lan = (const float*)d_in[1];   // lan_fs    [256,1,64]   fp32
  float* ws = (float*)d_ws;
  float* max0T = ws;                // [256*256]
  float* max1T = ws + 65536;        // [256*256]
  float* lossb = ws + 131072;       // [256]

  const int shmem = 2 * CHBL;       // 32 KB dynamic
  topk_sim_kernel<<<256, 512, shmem, stream>>>(F, lan, max0T, max1T);
  lse_kernel<<<256, 256, 0, stream>>>(max0T, max1T, lossb);
  mean_kernel<<<1, 256, 0, stream>>>(lossb, (float*)d_out);
}